// Round 1
// baseline (110.621 us; speedup 1.0000x reference)
//
#include <hip/hip_runtime.h>

// MeanAggregator: out[b,:] = mean over UNIQUE cols c in row-segment b of embed[c,:]
// row_idx sorted ascending; duplicate (row,col) pairs count once (.set semantics).
//
// B = 4096 rows, U = 50000, D = 300, E = 131072 (avg deg 32, max ~60).
//
// v2: 2 waves per row, split by FEATURE DIM (wave0: float4-chunks 0..37,
// wave1: chunks 38..74). Each wave dedups redundantly (no barrier, no
// cross-wave reduction) and gathers all uniques for its chunk slice.
// Grid 4096x128 = 8192 waves = 32 waves/CU; __launch_bounds__(128,8)
// forces VGPR<=64 so full occupancy is achievable -> 2x memory-level
// parallelism vs v1 (which was 16 waves/CU).

#define DFEAT  300
#define NCHUNK 75        // DFEAT / 4
#define CAP    128       // per-wave unique-col capacity (max realistic deg ~60)

__global__ __launch_bounds__(256) void build_rowptr(
    const int* __restrict__ row_idx, int E, int B, int* __restrict__ row_ptr)
{
    const int e = blockIdx.x * 256 + threadIdx.x;
    if (e >= E) return;
    const int r     = row_idx[e];
    const int rprev = (e == 0) ? -1 : row_idx[e - 1];
    for (int x = rprev + 1; x <= r; ++x) row_ptr[x] = e;   // lower_bound for rows (rprev, r]
    if (e == E - 1) {
        for (int x = r + 1; x <= B; ++x) row_ptr[x] = E;   // tail + row_ptr[B]
    }
}

__global__ __launch_bounds__(128, 8) void mean_agg_kernel(
    const int* __restrict__ row_ptr,
    const int* __restrict__ col_idx,
    const float* __restrict__ embed,
    float* __restrict__ out,
    int B)
{
    const int lane = threadIdx.x & 63;
    const int w    = threadIdx.x >> 6;      // 0 or 1: which feature-slice wave
    const int b    = blockIdx.x;            // one row per block
    if (b >= B) return;

    __shared__ int s_uniq[2][CAP];

    const int start = row_ptr[b];
    const int deg   = row_ptr[b + 1] - start;

    // ---- dedup + compact into s_uniq[w][0..cnt) (per-wave, redundant across
    // the 2 waves, deterministic -> identical cnt; no barriers) ----
    int cnt = 0;
    for (int base = 0; base < deg; base += 64) {
        const int  i     = base + lane;
        const bool valid = (i < deg);
        const int  c     = valid ? col_idx[start + i] : -1;

        bool dup = false;
        // vs uniques accepted in earlier chunks (uniform broadcast reads)
        for (int q = 0; q < cnt; ++q) dup = dup || (s_uniq[w][q] == c);
        // vs earlier lanes in this chunk
        const int jmax = (deg - base - 1 < 63) ? (deg - base - 1) : 63;
        for (int j = 0; j < jmax; ++j) {
            const int cj = __shfl(c, j);
            dup = dup || ((j < lane) && (cj == c));
        }

        const unsigned long long m = __ballot(valid && !dup);
        const int rank = __popcll(m & ((1ull << lane) - 1ull));
        if (valid && !dup) {
            const int p = cnt + rank;
            if (p < CAP) s_uniq[w][p] = c;
        }
        cnt += (int)__popcll(m);
    }
    if (cnt > CAP) cnt = CAP;   // unreachable for this dataset; safety only

    // ---- gather: wave w covers chunks [w*38, w*38 + nact), nact = 38 / 37 ----
    const int nact = w ? (NCHUNK - 38) : 38;    // 37 : 38
    const int ch   = lane + w * 38;             // this lane's float4 chunk
    if (lane < nact) {
        const uint32_t off = (uint32_t)ch * 16u;            // byte offset in row
        const char* __restrict__ eb = (const char*)embed;   // row c at byte c*1200

        float4 acc = {0.f, 0.f, 0.f, 0.f};

        int u = 0;
        int c0 = 0, c1 = 0, c2 = 0, c3 = 0;
        if (cnt >= 4) {
            c0 = s_uniq[w][0]; c1 = s_uniq[w][1];
            c2 = s_uniq[w][2]; c3 = s_uniq[w][3];
        }
        // 4-deep unrolled, next-quad indices prefetched past the vmem wait
        for (; u + 8 <= cnt; u += 4) {
            const float4 v0 = *(const float4*)(eb + ((uint32_t)c0 * 1200u + off));
            const float4 v1 = *(const float4*)(eb + ((uint32_t)c1 * 1200u + off));
            const float4 v2 = *(const float4*)(eb + ((uint32_t)c2 * 1200u + off));
            const float4 v3 = *(const float4*)(eb + ((uint32_t)c3 * 1200u + off));
            const int n0 = s_uniq[w][u + 4];
            const int n1 = s_uniq[w][u + 5];
            const int n2 = s_uniq[w][u + 6];
            const int n3 = s_uniq[w][u + 7];
            acc.x += v0.x + v1.x + v2.x + v3.x;
            acc.y += v0.y + v1.y + v2.y + v3.y;
            acc.z += v0.z + v1.z + v2.z + v3.z;
            acc.w += v0.w + v1.w + v2.w + v3.w;
            c0 = n0; c1 = n1; c2 = n2; c3 = n3;
        }
        if (u + 4 <= cnt) {     // last full quad (indices already in regs)
            const float4 v0 = *(const float4*)(eb + ((uint32_t)c0 * 1200u + off));
            const float4 v1 = *(const float4*)(eb + ((uint32_t)c1 * 1200u + off));
            const float4 v2 = *(const float4*)(eb + ((uint32_t)c2 * 1200u + off));
            const float4 v3 = *(const float4*)(eb + ((uint32_t)c3 * 1200u + off));
            acc.x += v0.x + v1.x + v2.x + v3.x;
            acc.y += v0.y + v1.y + v2.y + v3.y;
            acc.z += v0.z + v1.z + v2.z + v3.z;
            acc.w += v0.w + v1.w + v2.w + v3.w;
            u += 4;
        }
        for (; u < cnt; ++u) {
            const int cS = s_uniq[w][u];
            const float4 v = *(const float4*)(eb + ((uint32_t)cS * 1200u + off));
            acc.x += v.x; acc.y += v.y; acc.z += v.z; acc.w += v.w;
        }

        // ---- scale + store (waves write disjoint chunk ranges) ----
        const float s = (cnt > 0) ? (1.0f / (float)cnt) : 0.0f;
        float4 r;
        r.x = acc.x * s; r.y = acc.y * s; r.z = acc.z * s; r.w = acc.w * s;
        *(float4*)((char*)out + (size_t)b * 1200u + (uint32_t)ch * 16u) = r;
    }
}

extern "C" void kernel_launch(void* const* d_in, const int* in_sizes, int n_in,
                              void* d_out, int out_size, void* d_ws, size_t ws_size,
                              hipStream_t stream) {
    const int*   row_idx = (const int*)  d_in[0];
    const int*   col_idx = (const int*)  d_in[1];
    const float* embed   = (const float*)d_in[2];
    float*       out     = (float*)      d_out;

    const int E = in_sizes[0];            // 131072
    const int B = out_size / DFEAT;       // 4096

    int* row_ptr = (int*)d_ws;            // (B+1) ints, rebuilt every call

    build_rowptr<<<(E + 255) / 256, 256, 0, stream>>>(row_idx, E, B, row_ptr);
    mean_agg_kernel<<<B, 128, 0, stream>>>(row_ptr, col_idx, embed, out, B);
}